// Round 1
// baseline (492.263 us; speedup 1.0000x reference)
//
#include <hip/hip_runtime.h>
#include <hip/hip_bf16.h>

// GCN 2-layer: N=100000, E=3200000, F 512->16->40, fp32 in/out.
// Pipeline: bucket-hist -> scan -> LDS counting-sort binning -> per-bucket CSR
// build -> GEMM1 (W-in-regs, shuffle butterfly, bf16 out) ->
// gather1(+relu+bias, bf16 table, 2 lanes/node uint4) -> fused gather2+W2+log_softmax.
// bf16 tables: 3.2MB/node-table fits per-XCD L2 (4MB).
// This rev: gathers use 2 lanes/node with 16B uint4 loads (4x fewer vmem
// instrs, 4x less csr redundancy vs 8-lane scalar); offs/ends packed to int2.

#define NF0 512
#define NF1 16
#define NF2 40
#define BSHIFT 7            // 128 nodes per bucket
#define BNODES 128
#define CHUNK 8192          // edges per binsort block

// bf16 pair helpers: uint u = bf16(lo) | bf16(hi)<<16
__device__ __forceinline__ float bflo(unsigned int u) { return __uint_as_float(u << 16); }
__device__ __forceinline__ float bfhi(unsigned int u) { return __uint_as_float(u & 0xFFFF0000u); }
__device__ __forceinline__ unsigned int packbf(float lo, float hi) {
    unsigned int bl = __float_as_uint(lo);
    bl = (bl + 0x7FFFu + ((bl >> 16) & 1u)) >> 16;
    unsigned int bh = __float_as_uint(hi);
    bh = (bh + 0x7FFFu + ((bh >> 16) & 1u)) & 0xFFFF0000u;
    return bl | bh;
}

// ---------------- bucket histogram ----------------

__global__ void k_zero(int* __restrict__ p, int n) {
    int i = blockIdx.x * 256 + threadIdx.x;
    if (i < n) p[i] = 0;
}

__global__ __launch_bounds__(256) void k_hist(const int* __restrict__ dst,
                                              int* __restrict__ bhist, int E, int NB) {
    extern __shared__ int lh[];
    for (int i = threadIdx.x; i < NB; i += 256) lh[i] = 0;
    __syncthreads();
    for (int e = blockIdx.x * 256 + threadIdx.x; e < E; e += gridDim.x * 256)
        atomicAdd(&lh[dst[e] >> BSHIFT], 1);
    __syncthreads();
    for (int i = threadIdx.x; i < NB; i += 256) {
        int c = lh[i];
        if (c) atomicAdd(&bhist[i], c);
    }
}

__global__ __launch_bounds__(1024) void k_scan(const int* __restrict__ bhist,
                                               int* __restrict__ bstart,
                                               int* __restrict__ cursor, int NB) {
    __shared__ int s[1024];
    int t = threadIdx.x;
    s[t] = (t < NB) ? bhist[t] : 0;
    __syncthreads();
    for (int off = 1; off < 1024; off <<= 1) {
        int y = (t >= off) ? s[t - off] : 0;
        __syncthreads();
        s[t] += y;
        __syncthreads();
    }
    if (t < NB) {
        int excl = (t > 0) ? s[t - 1] : 0;
        bstart[t] = excl;
        cursor[t] = excl;
    }
    if (t == NB) bstart[NB] = s[NB - 1];
}

// ---------------- binning: counting sort CHUNK edges by bucket in LDS ----------------

__global__ __launch_bounds__(256) void k_binsort(
    const int* __restrict__ src, const int* __restrict__ dst,
    int* __restrict__ cursor, unsigned int* __restrict__ binned, int E, int NB) {
    __shared__ unsigned int sorted[CHUNK];
    __shared__ unsigned short bid[CHUNK];
    extern __shared__ int dyn[];
    int* hist = dyn;            // NB (reused as local cursor)
    int* lstart = dyn + NB;     // NB
    int* gbase = dyn + 2 * NB;  // NB
    __shared__ int wtot[4];

    const int t = threadIdx.x;
    const int lane = t & 63, wav = t >> 6;
    const int base = blockIdx.x * CHUNK;
    const int ne = min(CHUNK, E - base);

    for (int i = t; i < NB; i += 256) hist[i] = 0;
    __syncthreads();

    for (int i = t; i < ne; i += 256) atomicAdd(&hist[dst[base + i] >> BSHIFT], 1);
    __syncthreads();

    {
        int eb = t * 4;
        int loc[4];
        int tsum = 0;
        #pragma unroll
        for (int q = 0; q < 4; ++q) {
            loc[q] = (eb + q < NB) ? hist[eb + q] : 0;
            tsum += loc[q];
        }
        int v = tsum;
        #pragma unroll
        for (int off = 1; off < 64; off <<= 1) {
            int y = __shfl_up(v, off, 64);
            if (lane >= off) v += y;
        }
        if (lane == 63) wtot[wav] = v;
        __syncthreads();
        int wbase = 0;
        #pragma unroll
        for (int w = 0; w < 4; ++w) wbase += (w < wav) ? wtot[w] : 0;
        int run = wbase + v - tsum;
        #pragma unroll
        for (int q = 0; q < 4; ++q) {
            if (eb + q < NB) lstart[eb + q] = run;
            run += loc[q];
        }
    }
    __syncthreads();

    for (int b = t; b < NB; b += 256) {
        int c = hist[b];
        if (c > 0) gbase[b] = atomicAdd(&cursor[b], c);
        hist[b] = lstart[b];
    }
    __syncthreads();

    for (int i = t; i < ne; i += 256) {
        int d = dst[base + i];
        int s = src[base + i];
        int b = d >> BSHIFT;
        int pos = atomicAdd(&hist[b], 1);
        sorted[pos] = ((unsigned int)(d & (BNODES - 1)) << 20) | (unsigned int)s;
        bid[pos] = (unsigned short)b;
    }
    __syncthreads();

    for (int i = t; i < ne; i += 256) {
        int b = bid[i];
        binned[gbase[b] + (i - lstart[b])] = sorted[i];
    }
}

// ---------------- per-bucket CSR build ----------------

__global__ __launch_bounds__(256) void k_build(
    const unsigned int* __restrict__ binned, const int* __restrict__ bstart,
    int* __restrict__ csr, int2* __restrict__ oe,
    float* __restrict__ dinv, int n) {
    __shared__ int cnt[BNODES];
    __shared__ int lcur[BNODES];
    __shared__ int excl[BNODES];
    const int b = blockIdx.x;
    const int t = threadIdx.x;
    const int lane = t & 63, wav = t >> 6;
    const int s0 = bstart[b], s1 = bstart[b + 1];
    const int ne = s1 - s0;

    if (t < BNODES) cnt[t] = 0;
    __syncthreads();
    for (int i = t; i < ne; i += 256)
        atomicAdd(&cnt[(binned[s0 + i] >> 20) & (BNODES - 1)], 1);
    __syncthreads();

    if (wav == 0) {
        int c0 = cnt[2 * lane], c1 = cnt[2 * lane + 1];
        int v = c0 + c1;
        #pragma unroll
        for (int off = 1; off < 64; off <<= 1) {
            int y = __shfl_up(v, off, 64);
            if (lane >= off) v += y;
        }
        int ex = v - c0 - c1;
        excl[2 * lane] = ex;
        excl[2 * lane + 1] = ex + c0;
        lcur[2 * lane] = ex;
        lcur[2 * lane + 1] = ex + c0;
    }
    __syncthreads();

    if (t < BNODES) {
        int node = b * BNODES + t;
        if (node < n) {
            int deg = cnt[t] + 1;  // + self loop
            dinv[node] = rsqrtf((float)deg);
            int o = s0 + excl[t];
            oe[node] = make_int2(o, o + cnt[t]);
        }
    }
    __syncthreads();

    for (int i = t; i < ne; i += 256) {
        unsigned int v = binned[s0 + i];
        int dlow = (v >> 20) & (BNODES - 1);
        int p = atomicAdd(&lcur[dlow], 1);
        csr[s0 + p] = (int)(v & 0xFFFFFu);
    }
}

// ---------------- GEMM1: h1s[n][c] = bf16( dinv[n] * sum_k x[n][k]*W1[k][c] ) ----------
// One wave per row, barrier-free; W1 in 128 VGPRs; shuffle-butterfly reduce;
// 2-deep row prefetch. Output packed bf16 pairs (8 uints/row).

__global__ __launch_bounds__(256, 2) void k_gemm1(
    const float* __restrict__ x, const float* __restrict__ W1,
    const float* __restrict__ dinv, unsigned int* __restrict__ h1s, int n) {
    const int lane = threadIdx.x & 63;
    const int wav = threadIdx.x >> 6;

    float wA[4][16], wB[4][16];
    const float4* W1v = (const float4*)W1;
    #pragma unroll
    for (int j = 0; j < 4; ++j) {
        #pragma unroll
        for (int q = 0; q < 4; ++q) {
            float4 wa = W1v[(4 * lane + j) * 4 + q];
            wA[j][4 * q + 0] = wa.x; wA[j][4 * q + 1] = wa.y;
            wA[j][4 * q + 2] = wa.z; wA[j][4 * q + 3] = wa.w;
            float4 wb = W1v[(256 + 4 * lane + j) * 4 + q];
            wB[j][4 * q + 0] = wb.x; wB[j][4 * q + 1] = wb.y;
            wB[j][4 * q + 2] = wb.z; wB[j][4 * q + 3] = wb.w;
        }
    }

    const float4* xv = (const float4*)x;
    const int stride = gridDim.x * 4;

    auto process = [&](float4 p0, float4 p1, int r) {
        float part[16];
        #pragma unroll
        for (int c = 0; c < 16; ++c) part[c] = 0.f;
        float av[8] = {p0.x, p0.y, p0.z, p0.w, p1.x, p1.y, p1.z, p1.w};
        #pragma unroll
        for (int j = 0; j < 4; ++j) {
            #pragma unroll
            for (int c = 0; c < 16; ++c) {
                part[c] = fmaf(av[j], wA[j][c], part[c]);
                part[c] = fmaf(av[4 + j], wB[j][c], part[c]);
            }
        }
        const bool h5 = (lane & 32) != 0;
        float v8[8];
        #pragma unroll
        for (int j = 0; j < 8; ++j)
            v8[j] = (h5 ? part[j + 8] : part[j]) +
                    __shfl_xor(h5 ? part[j] : part[j + 8], 32, 64);
        const bool h4 = (lane & 16) != 0;
        float v4[4];
        #pragma unroll
        for (int j = 0; j < 4; ++j)
            v4[j] = (h4 ? v8[j + 4] : v8[j]) +
                    __shfl_xor(h4 ? v8[j] : v8[j + 4], 16, 64);
        const bool h3 = (lane & 8) != 0;
        float v2[2];
        #pragma unroll
        for (int j = 0; j < 2; ++j)
            v2[j] = (h3 ? v4[j + 2] : v4[j]) +
                    __shfl_xor(h3 ? v4[j] : v4[j + 2], 8, 64);
        const bool h2 = (lane & 4) != 0;
        float v1 = (h2 ? v2[1] : v2[0]) +
                   __shfl_xor(h2 ? v2[0] : v2[1], 4, 64);
        v1 += __shfl_xor(v1, 2, 64);
        v1 += __shfl_xor(v1, 1, 64);
        // every lane holds col (lane>>2); pair up cols (2p,2p+1) on lanes 8p
        float vnext = __shfl_down(v1, 4, 64);
        if ((lane & 7) == 0) {
            float di = dinv[r];
            h1s[(size_t)r * 8 + (lane >> 3)] = packbf(di * v1, di * vnext);
        }
    };

    int r0 = blockIdx.x * 4 + wav;
    int r1 = r0 + stride;
    float4 a0, a1, b0, b1;
    if (r0 < n) {
        a0 = xv[(size_t)r0 * 128 + lane];
        a1 = xv[(size_t)r0 * 128 + 64 + lane];
    }
    if (r1 < n) {
        b0 = xv[(size_t)r1 * 128 + lane];
        b1 = xv[(size_t)r1 * 128 + 64 + lane];
    }

    while (r0 < n) {
        float4 ca0 = a0, ca1 = a1;
        int pr = r0 + 2 * stride;
        if (pr < n) {
            a0 = xv[(size_t)pr * 128 + lane];
            a1 = xv[(size_t)pr * 128 + 64 + lane];
        }
        process(ca0, ca1, r0);
        if (r1 < n) {
            float4 cb0 = b0, cb1 = b1;
            int pr2 = r1 + 2 * stride;
            if (pr2 < n) {
                b0 = xv[(size_t)pr2 * 128 + lane];
                b1 = xv[(size_t)pr2 * 128 + 64 + lane];
            }
            process(cb0, cb1, r1);
        }
        r0 += 2 * stride;
        r1 += 2 * stride;
    }
}

// ---------------- gather1: 2 lanes/node, uint4 (16B) loads, 4-edge ILP ----------------

#define ACC8(A, u)                                         \
    do {                                                   \
        A[0] += bflo((u).x); A[1] += bfhi((u).x);          \
        A[2] += bflo((u).y); A[3] += bfhi((u).y);          \
        A[4] += bflo((u).z); A[5] += bfhi((u).z);          \
        A[6] += bflo((u).w); A[7] += bfhi((u).w);          \
    } while (0)

__global__ __launch_bounds__(256) void k_gather1(
    const int2* __restrict__ oe, const int* __restrict__ csr,
    const uint4* __restrict__ h1s, const float* __restrict__ dinv,
    const float* __restrict__ b1, uint4* __restrict__ hs2, int n) {
    int t = blockIdx.x * 256 + threadIdx.x;
    int node = t >> 1, p = t & 1;
    if (node >= n) return;
    int2 r = oe[node];
    int j = r.x, e = r.y;
    uint4 su = h1s[(size_t)node * 2 + p];  // self loop
    float A[8], B[8], C[8], D[8];
    #pragma unroll
    for (int k = 0; k < 8; ++k) { B[k] = 0.f; C[k] = 0.f; D[k] = 0.f; }
    ACC8(A, su);  // A starts from garbage? no: init then acc
    // fix: initialize A from su directly
    A[0] = bflo(su.x); A[1] = bfhi(su.x); A[2] = bflo(su.y); A[3] = bfhi(su.y);
    A[4] = bflo(su.z); A[5] = bfhi(su.z); A[6] = bflo(su.w); A[7] = bfhi(su.w);
    for (; j + 3 < e; j += 4) {
        int i0 = csr[j], i1 = csr[j + 1], i2 = csr[j + 2], i3 = csr[j + 3];
        uint4 u0 = h1s[(size_t)i0 * 2 + p];
        uint4 u1 = h1s[(size_t)i1 * 2 + p];
        uint4 u2 = h1s[(size_t)i2 * 2 + p];
        uint4 u3 = h1s[(size_t)i3 * 2 + p];
        ACC8(A, u0); ACC8(B, u1); ACC8(C, u2); ACC8(D, u3);
    }
    for (; j < e; ++j) {
        uint4 u = h1s[(size_t)csr[j] * 2 + p];
        ACC8(A, u);
    }
    float di = dinv[node];
    const float4* b1v = (const float4*)b1;
    float4 q0 = b1v[2 * p], q1 = b1v[2 * p + 1];
    float bias[8] = {q0.x, q0.y, q0.z, q0.w, q1.x, q1.y, q1.z, q1.w};
    float v[8];
    #pragma unroll
    for (int k = 0; k < 8; ++k) {
        float s = (A[k] + B[k]) + (C[k] + D[k]);
        v[k] = di * fmaxf(fmaf(di, s, bias[k]), 0.f);
    }
    uint4 o;
    o.x = packbf(v[0], v[1]); o.y = packbf(v[2], v[3]);
    o.z = packbf(v[4], v[5]); o.w = packbf(v[6], v[7]);
    hs2[(size_t)node * 2 + p] = o;
}

// ---------------- fused gather2 + W2 + b2 + log_softmax (2 lanes/node) ----------------

__global__ __launch_bounds__(256) void k_g2f(
    const int2* __restrict__ oe, const int* __restrict__ csr,
    const uint4* __restrict__ hs2, const float* __restrict__ dinv,
    const float* __restrict__ W2, const float* __restrict__ b2,
    float* __restrict__ out, int n) {
    __shared__ float w2s[NF1 * NF2];
    __shared__ float b2s[NF2];
    __shared__ float agg[128][17];
    for (int i = threadIdx.x; i < NF1 * NF2; i += 256) w2s[i] = W2[i];
    if (threadIdx.x < NF2) b2s[threadIdx.x] = b2[threadIdx.x];

    int t = blockIdx.x * 256 + threadIdx.x;
    int node = t >> 1, p = t & 1;
    int g = threadIdx.x >> 1;
    float v[8];
    #pragma unroll
    for (int k = 0; k < 8; ++k) v[k] = 0.f;
    if (node < n) {
        int2 r = oe[node];
        int j = r.x, e = r.y;
        uint4 su = hs2[(size_t)node * 2 + p];  // self loop
        float A[8], B[8], C[8], D[8];
        A[0] = bflo(su.x); A[1] = bfhi(su.x); A[2] = bflo(su.y); A[3] = bfhi(su.y);
        A[4] = bflo(su.z); A[5] = bfhi(su.z); A[6] = bflo(su.w); A[7] = bfhi(su.w);
        #pragma unroll
        for (int k = 0; k < 8; ++k) { B[k] = 0.f; C[k] = 0.f; D[k] = 0.f; }
        for (; j + 3 < e; j += 4) {
            int i0 = csr[j], i1 = csr[j + 1], i2 = csr[j + 2], i3 = csr[j + 3];
            uint4 u0 = hs2[(size_t)i0 * 2 + p];
            uint4 u1 = hs2[(size_t)i1 * 2 + p];
            uint4 u2 = hs2[(size_t)i2 * 2 + p];
            uint4 u3 = hs2[(size_t)i3 * 2 + p];
            ACC8(A, u0); ACC8(B, u1); ACC8(C, u2); ACC8(D, u3);
        }
        for (; j < e; ++j) {
            uint4 u = hs2[(size_t)csr[j] * 2 + p];
            ACC8(A, u);
        }
        float di = dinv[node];
        #pragma unroll
        for (int k = 0; k < 8; ++k)
            v[k] = ((A[k] + B[k]) + (C[k] + D[k])) * di;
    }
    #pragma unroll
    for (int k = 0; k < 8; ++k) agg[g][8 * p + k] = v[k];
    __syncthreads();

    int wav = threadIdx.x >> 6, lane = threadIdx.x & 63;
    int nbase = blockIdx.x * 128 + wav * 32;
    #pragma unroll 4
    for (int q = 0; q < 32; ++q) {
        int nd = nbase + q;
        if (nd >= n) break;  // nd uniform across wave
        float av[16];
        #pragma unroll
        for (int k = 0; k < 16; ++k) av[k] = agg[wav * 32 + q][k];
        float d = -1e30f;
        if (lane < NF2) {
            d = b2s[lane];
            #pragma unroll
            for (int k = 0; k < 16; ++k) d = fmaf(av[k], w2s[k * NF2 + lane], d);
        }
        float m = d;
        #pragma unroll
        for (int off = 32; off; off >>= 1) m = fmaxf(m, __shfl_xor(m, off, 64));
        float e2 = (lane < NF2) ? __expf(d - m) : 0.f;
        float ssum = e2;
        #pragma unroll
        for (int off = 32; off; off >>= 1) ssum += __shfl_xor(ssum, off, 64);
        float ls = __logf(ssum);
        if (lane < NF2) out[(size_t)nd * NF2 + lane] = d - m - ls;
    }
}

// ---------------- launch ----------------

extern "C" void kernel_launch(void* const* d_in, const int* in_sizes, int n_in,
                              void* d_out, int out_size, void* d_ws, size_t ws_size,
                              hipStream_t stream) {
    const float* x  = (const float*)d_in[0];
    const int*   ei = (const int*)d_in[1];
    const float* W1 = (const float*)d_in[2];
    const float* b1 = (const float*)d_in[3];
    const float* W2 = (const float*)d_in[4];
    const float* b2 = (const float*)d_in[5];
    float* out = (float*)d_out;

    const int N = in_sizes[0] / NF0;  // 100000
    const int E = in_sizes[1] / 2;    // 3200000
    const int NB = (N + BNODES - 1) / BNODES;  // 782
    const int* src = ei;
    const int* dst = ei + E;

    char* ws = (char*)d_ws;
    size_t off = 0;
    auto alloc = [&](size_t bytes) -> void* {
        void* p = ws + off;
        off = (off + bytes + 255) & ~(size_t)255;
        return p;
    };
    int*   bhist  = (int*)alloc((size_t)NB * 4);
    int*   bstart = (int*)alloc((size_t)(NB + 1) * 4);
    int*   cursor = (int*)alloc((size_t)NB * 4);
    unsigned int* binned = (unsigned int*)alloc((size_t)E * 4);
    int*   csr    = (int*)alloc((size_t)E * 4);
    int2*  oe     = (int2*)alloc((size_t)N * 8);
    float* dinv   = (float*)alloc((size_t)N * 4);
    // binned dead after k_build: reuse for bf16 h1s/hs2 (3.2MB each)
    unsigned int* h1s = binned;
    unsigned int* hs2 = binned + (size_t)N * 8;

    const int eb = (E + CHUNK - 1) / CHUNK;  // 391
    const size_t histBytes = (size_t)NB * 4;
    const int gthreads = (2 * N + 255) / 256;  // blocks for 2-lane gathers

    k_zero   <<<(NB + 255) / 256, 256, 0, stream>>>(bhist, NB);
    k_hist   <<<512, 256, histBytes, stream>>>(dst, bhist, E, NB);
    k_scan   <<<1, 1024, 0, stream>>>(bhist, bstart, cursor, NB);
    k_binsort<<<eb, 256, 3 * histBytes, stream>>>(src, dst, cursor, binned, E, NB);
    k_build  <<<NB, 256, 0, stream>>>(binned, bstart, csr, oe, dinv, N);
    k_gemm1  <<<1024, 256, 0, stream>>>(x, W1, dinv, h1s, N);
    k_gather1<<<gthreads, 256, 0, stream>>>(oe, csr, (const uint4*)h1s, dinv, b1,
                                            (uint4*)hs2, N);
    k_g2f    <<<gthreads, 256, 0, stream>>>(oe, csr, (const uint4*)hs2, dinv, W2, b2,
                                            out, N);
}

// Round 2
// 460.772 us; speedup vs baseline: 1.0683x; 1.0683x over previous
//
#include <hip/hip_runtime.h>
#include <hip/hip_bf16.h>

// GCN 2-layer: N=100000, E=3200000, F 512->16->40, fp32 in/out.
// Pipeline: bucket-hist -> scan -> LDS counting-sort binning -> per-bucket CSR
// build -> GEMM1 (W-in-regs, shuffle butterfly, bf16 out) ->
// gather1(+relu+bias) -> fused gather2+W2+log_softmax.
// bf16 tables: 3.2MB/node-table fits per-XCD L2 (4MB).
// This rev: gathers use 8 lanes/node = 4 edge-segments x 2 feature-halves.
// Each lane does uint4 (16B) table loads over deg/4 edges; segment partials
// combined via __shfl_xor(2)/(4). Full 800K-thread occupancy (latency hiding)
// AND 4x fewer vmem instructions than the scalar 8-lane version.

#define NF0 512
#define NF1 16
#define NF2 40
#define BSHIFT 7            // 128 nodes per bucket
#define BNODES 128
#define CHUNK 8192          // edges per binsort block

// bf16 pair helpers: uint u = bf16(lo) | bf16(hi)<<16
__device__ __forceinline__ float bflo(unsigned int u) { return __uint_as_float(u << 16); }
__device__ __forceinline__ float bfhi(unsigned int u) { return __uint_as_float(u & 0xFFFF0000u); }
__device__ __forceinline__ unsigned int packbf(float lo, float hi) {
    unsigned int bl = __float_as_uint(lo);
    bl = (bl + 0x7FFFu + ((bl >> 16) & 1u)) >> 16;
    unsigned int bh = __float_as_uint(hi);
    bh = (bh + 0x7FFFu + ((bh >> 16) & 1u)) & 0xFFFF0000u;
    return bl | bh;
}

#define ACC8(A, u)                                         \
    do {                                                   \
        A[0] += bflo((u).x); A[1] += bfhi((u).x);          \
        A[2] += bflo((u).y); A[3] += bfhi((u).y);          \
        A[4] += bflo((u).z); A[5] += bfhi((u).z);          \
        A[6] += bflo((u).w); A[7] += bfhi((u).w);          \
    } while (0)

// ---------------- bucket histogram ----------------

__global__ void k_zero(int* __restrict__ p, int n) {
    int i = blockIdx.x * 256 + threadIdx.x;
    if (i < n) p[i] = 0;
}

__global__ __launch_bounds__(256) void k_hist(const int* __restrict__ dst,
                                              int* __restrict__ bhist, int E, int NB) {
    extern __shared__ int lh[];
    for (int i = threadIdx.x; i < NB; i += 256) lh[i] = 0;
    __syncthreads();
    for (int e = blockIdx.x * 256 + threadIdx.x; e < E; e += gridDim.x * 256)
        atomicAdd(&lh[dst[e] >> BSHIFT], 1);
    __syncthreads();
    for (int i = threadIdx.x; i < NB; i += 256) {
        int c = lh[i];
        if (c) atomicAdd(&bhist[i], c);
    }
}

__global__ __launch_bounds__(1024) void k_scan(const int* __restrict__ bhist,
                                               int* __restrict__ bstart,
                                               int* __restrict__ cursor, int NB) {
    __shared__ int s[1024];
    int t = threadIdx.x;
    s[t] = (t < NB) ? bhist[t] : 0;
    __syncthreads();
    for (int off = 1; off < 1024; off <<= 1) {
        int y = (t >= off) ? s[t - off] : 0;
        __syncthreads();
        s[t] += y;
        __syncthreads();
    }
    if (t < NB) {
        int excl = (t > 0) ? s[t - 1] : 0;
        bstart[t] = excl;
        cursor[t] = excl;
    }
    if (t == NB) bstart[NB] = s[NB - 1];
}

// ---------------- binning: counting sort CHUNK edges by bucket in LDS ----------------

__global__ __launch_bounds__(256) void k_binsort(
    const int* __restrict__ src, const int* __restrict__ dst,
    int* __restrict__ cursor, unsigned int* __restrict__ binned, int E, int NB) {
    __shared__ unsigned int sorted[CHUNK];
    __shared__ unsigned short bid[CHUNK];
    extern __shared__ int dyn[];
    int* hist = dyn;            // NB (reused as local cursor)
    int* lstart = dyn + NB;     // NB
    int* gbase = dyn + 2 * NB;  // NB
    __shared__ int wtot[4];

    const int t = threadIdx.x;
    const int lane = t & 63, wav = t >> 6;
    const int base = blockIdx.x * CHUNK;
    const int ne = min(CHUNK, E - base);

    for (int i = t; i < NB; i += 256) hist[i] = 0;
    __syncthreads();

    for (int i = t; i < ne; i += 256) atomicAdd(&hist[dst[base + i] >> BSHIFT], 1);
    __syncthreads();

    {
        int eb = t * 4;
        int loc[4];
        int tsum = 0;
        #pragma unroll
        for (int q = 0; q < 4; ++q) {
            loc[q] = (eb + q < NB) ? hist[eb + q] : 0;
            tsum += loc[q];
        }
        int v = tsum;
        #pragma unroll
        for (int off = 1; off < 64; off <<= 1) {
            int y = __shfl_up(v, off, 64);
            if (lane >= off) v += y;
        }
        if (lane == 63) wtot[wav] = v;
        __syncthreads();
        int wbase = 0;
        #pragma unroll
        for (int w = 0; w < 4; ++w) wbase += (w < wav) ? wtot[w] : 0;
        int run = wbase + v - tsum;
        #pragma unroll
        for (int q = 0; q < 4; ++q) {
            if (eb + q < NB) lstart[eb + q] = run;
            run += loc[q];
        }
    }
    __syncthreads();

    for (int b = t; b < NB; b += 256) {
        int c = hist[b];
        if (c > 0) gbase[b] = atomicAdd(&cursor[b], c);
        hist[b] = lstart[b];
    }
    __syncthreads();

    for (int i = t; i < ne; i += 256) {
        int d = dst[base + i];
        int s = src[base + i];
        int b = d >> BSHIFT;
        int pos = atomicAdd(&hist[b], 1);
        sorted[pos] = ((unsigned int)(d & (BNODES - 1)) << 20) | (unsigned int)s;
        bid[pos] = (unsigned short)b;
    }
    __syncthreads();

    for (int i = t; i < ne; i += 256) {
        int b = bid[i];
        binned[gbase[b] + (i - lstart[b])] = sorted[i];
    }
}

// ---------------- per-bucket CSR build ----------------

__global__ __launch_bounds__(256) void k_build(
    const unsigned int* __restrict__ binned, const int* __restrict__ bstart,
    int* __restrict__ csr, int2* __restrict__ oe,
    float* __restrict__ dinv, int n) {
    __shared__ int cnt[BNODES];
    __shared__ int lcur[BNODES];
    __shared__ int excl[BNODES];
    const int b = blockIdx.x;
    const int t = threadIdx.x;
    const int lane = t & 63, wav = t >> 6;
    const int s0 = bstart[b], s1 = bstart[b + 1];
    const int ne = s1 - s0;

    if (t < BNODES) cnt[t] = 0;
    __syncthreads();
    for (int i = t; i < ne; i += 256)
        atomicAdd(&cnt[(binned[s0 + i] >> 20) & (BNODES - 1)], 1);
    __syncthreads();

    if (wav == 0) {
        int c0 = cnt[2 * lane], c1 = cnt[2 * lane + 1];
        int v = c0 + c1;
        #pragma unroll
        for (int off = 1; off < 64; off <<= 1) {
            int y = __shfl_up(v, off, 64);
            if (lane >= off) v += y;
        }
        int ex = v - c0 - c1;
        excl[2 * lane] = ex;
        excl[2 * lane + 1] = ex + c0;
        lcur[2 * lane] = ex;
        lcur[2 * lane + 1] = ex + c0;
    }
    __syncthreads();

    if (t < BNODES) {
        int node = b * BNODES + t;
        if (node < n) {
            int deg = cnt[t] + 1;  // + self loop
            dinv[node] = rsqrtf((float)deg);
            int o = s0 + excl[t];
            oe[node] = make_int2(o, o + cnt[t]);
        }
    }
    __syncthreads();

    for (int i = t; i < ne; i += 256) {
        unsigned int v = binned[s0 + i];
        int dlow = (v >> 20) & (BNODES - 1);
        int p = atomicAdd(&lcur[dlow], 1);
        csr[s0 + p] = (int)(v & 0xFFFFFu);
    }
}

// ---------------- GEMM1: h1s[n][c] = bf16( dinv[n] * sum_k x[n][k]*W1[k][c] ) ----------
// One wave per row, barrier-free; W1 in 128 VGPRs; shuffle-butterfly reduce;
// 2-deep row prefetch. Output packed bf16 pairs (8 uints/row).

__global__ __launch_bounds__(256, 2) void k_gemm1(
    const float* __restrict__ x, const float* __restrict__ W1,
    const float* __restrict__ dinv, unsigned int* __restrict__ h1s, int n) {
    const int lane = threadIdx.x & 63;
    const int wav = threadIdx.x >> 6;

    float wA[4][16], wB[4][16];
    const float4* W1v = (const float4*)W1;
    #pragma unroll
    for (int j = 0; j < 4; ++j) {
        #pragma unroll
        for (int q = 0; q < 4; ++q) {
            float4 wa = W1v[(4 * lane + j) * 4 + q];
            wA[j][4 * q + 0] = wa.x; wA[j][4 * q + 1] = wa.y;
            wA[j][4 * q + 2] = wa.z; wA[j][4 * q + 3] = wa.w;
            float4 wb = W1v[(256 + 4 * lane + j) * 4 + q];
            wB[j][4 * q + 0] = wb.x; wB[j][4 * q + 1] = wb.y;
            wB[j][4 * q + 2] = wb.z; wB[j][4 * q + 3] = wb.w;
        }
    }

    const float4* xv = (const float4*)x;
    const int stride = gridDim.x * 4;

    auto process = [&](float4 p0, float4 p1, int r) {
        float part[16];
        #pragma unroll
        for (int c = 0; c < 16; ++c) part[c] = 0.f;
        float av[8] = {p0.x, p0.y, p0.z, p0.w, p1.x, p1.y, p1.z, p1.w};
        #pragma unroll
        for (int j = 0; j < 4; ++j) {
            #pragma unroll
            for (int c = 0; c < 16; ++c) {
                part[c] = fmaf(av[j], wA[j][c], part[c]);
                part[c] = fmaf(av[4 + j], wB[j][c], part[c]);
            }
        }
        const bool h5 = (lane & 32) != 0;
        float v8[8];
        #pragma unroll
        for (int j = 0; j < 8; ++j)
            v8[j] = (h5 ? part[j + 8] : part[j]) +
                    __shfl_xor(h5 ? part[j] : part[j + 8], 32, 64);
        const bool h4 = (lane & 16) != 0;
        float v4[4];
        #pragma unroll
        for (int j = 0; j < 4; ++j)
            v4[j] = (h4 ? v8[j + 4] : v8[j]) +
                    __shfl_xor(h4 ? v8[j] : v8[j + 4], 16, 64);
        const bool h3 = (lane & 8) != 0;
        float v2[2];
        #pragma unroll
        for (int j = 0; j < 2; ++j)
            v2[j] = (h3 ? v4[j + 2] : v4[j]) +
                    __shfl_xor(h3 ? v4[j] : v4[j + 2], 8, 64);
        const bool h2 = (lane & 4) != 0;
        float v1 = (h2 ? v2[1] : v2[0]) +
                   __shfl_xor(h2 ? v2[0] : v2[1], 4, 64);
        v1 += __shfl_xor(v1, 2, 64);
        v1 += __shfl_xor(v1, 1, 64);
        // every lane holds col (lane>>2); pair up cols (2p,2p+1) on lanes 8p
        float vnext = __shfl_down(v1, 4, 64);
        if ((lane & 7) == 0) {
            float di = dinv[r];
            h1s[(size_t)r * 8 + (lane >> 3)] = packbf(di * v1, di * vnext);
        }
    };

    int r0 = blockIdx.x * 4 + wav;
    int r1 = r0 + stride;
    float4 a0, a1, b0, b1;
    if (r0 < n) {
        a0 = xv[(size_t)r0 * 128 + lane];
        a1 = xv[(size_t)r0 * 128 + 64 + lane];
    }
    if (r1 < n) {
        b0 = xv[(size_t)r1 * 128 + lane];
        b1 = xv[(size_t)r1 * 128 + 64 + lane];
    }

    while (r0 < n) {
        float4 ca0 = a0, ca1 = a1;
        int pr = r0 + 2 * stride;
        if (pr < n) {
            a0 = xv[(size_t)pr * 128 + lane];
            a1 = xv[(size_t)pr * 128 + 64 + lane];
        }
        process(ca0, ca1, r0);
        if (r1 < n) {
            float4 cb0 = b0, cb1 = b1;
            int pr2 = r1 + 2 * stride;
            if (pr2 < n) {
                b0 = xv[(size_t)pr2 * 128 + lane];
                b1 = xv[(size_t)pr2 * 128 + 64 + lane];
            }
            process(cb0, cb1, r1);
        }
        r0 += 2 * stride;
        r1 += 2 * stride;
    }
}

// ---------------- gather1: 8 lanes/node = 4 segs x 2 halves, uint4 loads ----------------
// seg walks deg/4 edges; partials combined via shfl_xor lanes (2,4).

__global__ __launch_bounds__(256) void k_gather1(
    const int2* __restrict__ oe, const int* __restrict__ csr,
    const uint4* __restrict__ h1s, const float* __restrict__ dinv,
    const float* __restrict__ b1, uint4* __restrict__ hs2, int n) {
    int t = blockIdx.x * 256 + threadIdx.x;
    int node = t >> 3;
    if (node >= n) return;
    const int sub = t & 7, seg = sub >> 1, p = sub & 1;
    int2 r = oe[node];
    const int d = r.y - r.x;
    int j = r.x + ((d * seg) >> 2);
    const int e = r.x + ((d * (seg + 1)) >> 2);
    const char* tab = (const char*)h1s;
    const unsigned pof = (unsigned)(p << 4);

    float A[8], B[8];
    #pragma unroll
    for (int k = 0; k < 8; ++k) { A[k] = 0.f; B[k] = 0.f; }
    if (seg == 0) {  // self loop
        uint4 su = *(const uint4*)(tab + (((unsigned)node << 5) | pof));
        ACC8(A, su);
    }
    for (; j + 1 < e; j += 2) {
        int i0 = csr[j], i1 = csr[j + 1];
        uint4 u0 = *(const uint4*)(tab + (((unsigned)i0 << 5) | pof));
        uint4 u1 = *(const uint4*)(tab + (((unsigned)i1 << 5) | pof));
        ACC8(A, u0); ACC8(B, u1);
    }
    if (j < e) {
        uint4 u = *(const uint4*)(tab + (((unsigned)csr[j] << 5) | pof));
        ACC8(A, u);
    }
    float v[8];
    #pragma unroll
    for (int k = 0; k < 8; ++k) v[k] = A[k] + B[k];
    #pragma unroll
    for (int k = 0; k < 8; ++k) {
        v[k] += __shfl_xor(v[k], 2, 64);
        v[k] += __shfl_xor(v[k], 4, 64);
    }
    if (seg == 0) {
        float di = dinv[node];
        const float4* b1v = (const float4*)b1;
        float4 q0 = b1v[2 * p], q1 = b1v[2 * p + 1];
        float bias[8] = {q0.x, q0.y, q0.z, q0.w, q1.x, q1.y, q1.z, q1.w};
        float o[8];
        #pragma unroll
        for (int k = 0; k < 8; ++k)
            o[k] = di * fmaxf(fmaf(di, v[k], bias[k]), 0.f);
        uint4 w;
        w.x = packbf(o[0], o[1]); w.y = packbf(o[2], o[3]);
        w.z = packbf(o[4], o[5]); w.w = packbf(o[6], o[7]);
        *(uint4*)((char*)hs2 + (((unsigned)node << 5) | pof)) = w;
    }
}

// ---------------- fused gather2 + W2 + b2 + log_softmax ----------------
// Phase 1: same 8-lanes/node seg-split gather. Phase 2: 8 nodes/wave MLP+softmax.

__global__ __launch_bounds__(256) void k_g2f(
    const int2* __restrict__ oe, const int* __restrict__ csr,
    const uint4* __restrict__ hs2, const float* __restrict__ dinv,
    const float* __restrict__ W2, const float* __restrict__ b2,
    float* __restrict__ out, int n) {
    __shared__ float w2s[NF1 * NF2];
    __shared__ float b2s[NF2];
    __shared__ float agg[32][17];
    for (int i = threadIdx.x; i < NF1 * NF2; i += 256) w2s[i] = W2[i];
    if (threadIdx.x < NF2) b2s[threadIdx.x] = b2[threadIdx.x];

    int t = blockIdx.x * 256 + threadIdx.x;
    int node = t >> 3;
    const int sub = t & 7, seg = sub >> 1, p = sub & 1;
    const int g = threadIdx.x >> 3;

    if (node < n) {
        int2 r = oe[node];
        const int d = r.y - r.x;
        int j = r.x + ((d * seg) >> 2);
        const int e = r.x + ((d * (seg + 1)) >> 2);
        const char* tab = (const char*)hs2;
        const unsigned pof = (unsigned)(p << 4);

        float A[8], B[8];
        #pragma unroll
        for (int k = 0; k < 8; ++k) { A[k] = 0.f; B[k] = 0.f; }
        if (seg == 0) {  // self loop
            uint4 su = *(const uint4*)(tab + (((unsigned)node << 5) | pof));
            ACC8(A, su);
        }
        for (; j + 1 < e; j += 2) {
            int i0 = csr[j], i1 = csr[j + 1];
            uint4 u0 = *(const uint4*)(tab + (((unsigned)i0 << 5) | pof));
            uint4 u1 = *(const uint4*)(tab + (((unsigned)i1 << 5) | pof));
            ACC8(A, u0); ACC8(B, u1);
        }
        if (j < e) {
            uint4 u = *(const uint4*)(tab + (((unsigned)csr[j] << 5) | pof));
            ACC8(A, u);
        }
        float v[8];
        #pragma unroll
        for (int k = 0; k < 8; ++k) v[k] = A[k] + B[k];
        #pragma unroll
        for (int k = 0; k < 8; ++k) {
            v[k] += __shfl_xor(v[k], 2, 64);
            v[k] += __shfl_xor(v[k], 4, 64);
        }
        if (seg == 0) {
            float di = dinv[node];
            #pragma unroll
            for (int k = 0; k < 8; ++k) agg[g][8 * p + k] = v[k] * di;
        }
    }
    __syncthreads();

    int wav = threadIdx.x >> 6, lane = threadIdx.x & 63;
    int nbase = blockIdx.x * 32 + wav * 8;
    #pragma unroll
    for (int q = 0; q < 8; ++q) {
        int nd = nbase + q;
        if (nd >= n) break;  // nd uniform across wave
        float av[16];
        #pragma unroll
        for (int k = 0; k < 16; ++k) av[k] = agg[wav * 8 + q][k];
        float d = -1e30f;
        if (lane < NF2) {
            d = b2s[lane];
            #pragma unroll
            for (int k = 0; k < 16; ++k) d = fmaf(av[k], w2s[k * NF2 + lane], d);
        }
        float m = d;
        #pragma unroll
        for (int off = 32; off; off >>= 1) m = fmaxf(m, __shfl_xor(m, off, 64));
        float e2 = (lane < NF2) ? __expf(d - m) : 0.f;
        float ssum = e2;
        #pragma unroll
        for (int off = 32; off; off >>= 1) ssum += __shfl_xor(ssum, off, 64);
        float ls = __logf(ssum);
        if (lane < NF2) out[(size_t)nd * NF2 + lane] = d - m - ls;
    }
}

// ---------------- launch ----------------

extern "C" void kernel_launch(void* const* d_in, const int* in_sizes, int n_in,
                              void* d_out, int out_size, void* d_ws, size_t ws_size,
                              hipStream_t stream) {
    const float* x  = (const float*)d_in[0];
    const int*   ei = (const int*)d_in[1];
    const float* W1 = (const float*)d_in[2];
    const float* b1 = (const float*)d_in[3];
    const float* W2 = (const float*)d_in[4];
    const float* b2 = (const float*)d_in[5];
    float* out = (float*)d_out;

    const int N = in_sizes[0] / NF0;  // 100000
    const int E = in_sizes[1] / 2;    // 3200000
    const int NB = (N + BNODES - 1) / BNODES;  // 782
    const int* src = ei;
    const int* dst = ei + E;

    char* ws = (char*)d_ws;
    size_t off = 0;
    auto alloc = [&](size_t bytes) -> void* {
        void* p = ws + off;
        off = (off + bytes + 255) & ~(size_t)255;
        return p;
    };
    int*   bhist  = (int*)alloc((size_t)NB * 4);
    int*   bstart = (int*)alloc((size_t)(NB + 1) * 4);
    int*   cursor = (int*)alloc((size_t)NB * 4);
    unsigned int* binned = (unsigned int*)alloc((size_t)E * 4);
    int*   csr    = (int*)alloc((size_t)E * 4);
    int2*  oe     = (int2*)alloc((size_t)N * 8);
    float* dinv   = (float*)alloc((size_t)N * 4);
    // binned dead after k_build: reuse for bf16 h1s/hs2 (3.2MB each)
    unsigned int* h1s = binned;
    unsigned int* hs2 = binned + (size_t)N * 8;

    const int eb = (E + CHUNK - 1) / CHUNK;  // 391
    const size_t histBytes = (size_t)NB * 4;
    const int gblocks = (N * 8 + 255) / 256;  // 8 lanes/node

    k_zero   <<<(NB + 255) / 256, 256, 0, stream>>>(bhist, NB);
    k_hist   <<<512, 256, histBytes, stream>>>(dst, bhist, E, NB);
    k_scan   <<<1, 1024, 0, stream>>>(bhist, bstart, cursor, NB);
    k_binsort<<<eb, 256, 3 * histBytes, stream>>>(src, dst, cursor, binned, E, NB);
    k_build  <<<NB, 256, 0, stream>>>(binned, bstart, csr, oe, dinv, N);
    k_gemm1  <<<1024, 256, 0, stream>>>(x, W1, dinv, h1s, N);
    k_gather1<<<gblocks, 256, 0, stream>>>(oe, csr, (const uint4*)h1s, dinv, b1,
                                           (uint4*)hs2, N);
    k_g2f    <<<gblocks, 256, 0, stream>>>(oe, csr, (const uint4*)hs2, dinv, W2, b2,
                                           out, N);
}

// Round 3
// 442.534 us; speedup vs baseline: 1.1124x; 1.0412x over previous
//
#include <hip/hip_runtime.h>
#include <hip/hip_bf16.h>

// GCN 2-layer: N=100000, E=3200000, F 512->16->40, fp32 in/out.
// Pipeline (6 dispatches): zero-cursors -> LDS counting-sort binning into
// SLOTTED buckets (fixed MAXPB slots per bucket; no hist/scan needed) ->
// per-bucket CSR build -> GEMM1 (W-in-regs, shuffle butterfly, bf16 out) ->
// gather1(+relu+bias) -> fused gather2+W2+log_softmax.
// bf16 tables: 3.2MB/node-table fits per-XCD L2 (4MB).
// Gathers: 8 lanes/node = 4 edge-segments x 2 feature-halves, uint4 loads,
// 4-deep load ILP; segment partials combined via __shfl_xor(2)/(4).

#define NF0 512
#define NF1 16
#define NF2 40
#define BSHIFT 7            // 128 nodes per bucket
#define BNODES 128
#define CHUNK 8192          // edges per binsort block
#define MAXPB 5120          // slots per bucket; mean 4096, sigma 64 -> +16 sigma

// bf16 pair helpers: uint u = bf16(lo) | bf16(hi)<<16
__device__ __forceinline__ float bflo(unsigned int u) { return __uint_as_float(u << 16); }
__device__ __forceinline__ float bfhi(unsigned int u) { return __uint_as_float(u & 0xFFFF0000u); }
__device__ __forceinline__ unsigned int packbf(float lo, float hi) {
    unsigned int bl = __float_as_uint(lo);
    bl = (bl + 0x7FFFu + ((bl >> 16) & 1u)) >> 16;
    unsigned int bh = __float_as_uint(hi);
    bh = (bh + 0x7FFFu + ((bh >> 16) & 1u)) & 0xFFFF0000u;
    return bl | bh;
}

#define ACC8(A, u)                                         \
    do {                                                   \
        A[0] += bflo((u).x); A[1] += bfhi((u).x);          \
        A[2] += bflo((u).y); A[3] += bfhi((u).y);          \
        A[4] += bflo((u).z); A[5] += bfhi((u).z);          \
        A[6] += bflo((u).w); A[7] += bfhi((u).w);          \
    } while (0)

// ---------------- zero bucket cursors ----------------

__global__ void k_zero(int* __restrict__ p, int n) {
    int i = blockIdx.x * 256 + threadIdx.x;
    if (i < n) p[i] = 0;
}

// ---------------- binning: counting sort CHUNK edges by bucket in LDS ----------------
// Writes into slotted layout binned[b*MAXPB + slot]; cursor[b] ends as count.

__global__ __launch_bounds__(256) void k_binsort(
    const int* __restrict__ src, const int* __restrict__ dst,
    int* __restrict__ cursor, unsigned int* __restrict__ binned, int E, int NB) {
    __shared__ unsigned int sorted[CHUNK];
    __shared__ unsigned short bid[CHUNK];
    extern __shared__ int dyn[];
    int* hist = dyn;            // NB (reused as local cursor)
    int* lstart = dyn + NB;     // NB
    int* gbase = dyn + 2 * NB;  // NB
    __shared__ int wtot[4];

    const int t = threadIdx.x;
    const int lane = t & 63, wav = t >> 6;
    const int base = blockIdx.x * CHUNK;
    const int ne = min(CHUNK, E - base);

    for (int i = t; i < NB; i += 256) hist[i] = 0;
    __syncthreads();

    for (int i = t; i < ne; i += 256) atomicAdd(&hist[dst[base + i] >> BSHIFT], 1);
    __syncthreads();

    {
        int eb = t * 4;
        int loc[4];
        int tsum = 0;
        #pragma unroll
        for (int q = 0; q < 4; ++q) {
            loc[q] = (eb + q < NB) ? hist[eb + q] : 0;
            tsum += loc[q];
        }
        int v = tsum;
        #pragma unroll
        for (int off = 1; off < 64; off <<= 1) {
            int y = __shfl_up(v, off, 64);
            if (lane >= off) v += y;
        }
        if (lane == 63) wtot[wav] = v;
        __syncthreads();
        int wbase = 0;
        #pragma unroll
        for (int w = 0; w < 4; ++w) wbase += (w < wav) ? wtot[w] : 0;
        int run = wbase + v - tsum;
        #pragma unroll
        for (int q = 0; q < 4; ++q) {
            if (eb + q < NB) lstart[eb + q] = run;
            run += loc[q];
        }
    }
    __syncthreads();

    for (int b = t; b < NB; b += 256) {
        int c = hist[b];
        if (c > 0) gbase[b] = b * MAXPB + atomicAdd(&cursor[b], c);
        hist[b] = lstart[b];
    }
    __syncthreads();

    for (int i = t; i < ne; i += 256) {
        int d = dst[base + i];
        int s = src[base + i];
        int b = d >> BSHIFT;
        int pos = atomicAdd(&hist[b], 1);
        sorted[pos] = ((unsigned int)(d & (BNODES - 1)) << 20) | (unsigned int)s;
        bid[pos] = (unsigned short)b;
    }
    __syncthreads();

    for (int i = t; i < ne; i += 256) {
        int b = bid[i];
        binned[gbase[b] + (i - lstart[b])] = sorted[i];
    }
}

// ---------------- per-bucket CSR build (slotted) ----------------

__global__ __launch_bounds__(256) void k_build(
    const unsigned int* __restrict__ binned, const int* __restrict__ cnt_in,
    int* __restrict__ csr, int2* __restrict__ oe,
    float* __restrict__ dinv, int n) {
    __shared__ int cnt[BNODES];
    __shared__ int lcur[BNODES];
    __shared__ int excl[BNODES];
    const int b = blockIdx.x;
    const int t = threadIdx.x;
    const int lane = t & 63, wav = t >> 6;
    const int s0 = b * MAXPB;
    const int ne = cnt_in[b];

    if (t < BNODES) cnt[t] = 0;
    __syncthreads();
    for (int i = t; i < ne; i += 256)
        atomicAdd(&cnt[(binned[s0 + i] >> 20) & (BNODES - 1)], 1);
    __syncthreads();

    if (wav == 0) {
        int c0 = cnt[2 * lane], c1 = cnt[2 * lane + 1];
        int v = c0 + c1;
        #pragma unroll
        for (int off = 1; off < 64; off <<= 1) {
            int y = __shfl_up(v, off, 64);
            if (lane >= off) v += y;
        }
        int ex = v - c0 - c1;
        excl[2 * lane] = ex;
        excl[2 * lane + 1] = ex + c0;
        lcur[2 * lane] = ex;
        lcur[2 * lane + 1] = ex + c0;
    }
    __syncthreads();

    if (t < BNODES) {
        int node = b * BNODES + t;
        if (node < n) {
            int deg = cnt[t] + 1;  // + self loop
            dinv[node] = rsqrtf((float)deg);
            int o = s0 + excl[t];
            oe[node] = make_int2(o, o + cnt[t]);
        }
    }
    __syncthreads();

    for (int i = t; i < ne; i += 256) {
        unsigned int v = binned[s0 + i];
        int dlow = (v >> 20) & (BNODES - 1);
        int p = atomicAdd(&lcur[dlow], 1);
        csr[s0 + p] = (int)(v & 0xFFFFFu);
    }
}

// ---------------- GEMM1: h1s[n][c] = bf16( dinv[n] * sum_k x[n][k]*W1[k][c] ) ----------
// One wave per row, barrier-free; W1 in 128 VGPRs; shuffle-butterfly reduce;
// 2-deep row prefetch. Output packed bf16 pairs (8 uints/row).

__global__ __launch_bounds__(256, 2) void k_gemm1(
    const float* __restrict__ x, const float* __restrict__ W1,
    const float* __restrict__ dinv, unsigned int* __restrict__ h1s, int n) {
    const int lane = threadIdx.x & 63;
    const int wav = threadIdx.x >> 6;

    float wA[4][16], wB[4][16];
    const float4* W1v = (const float4*)W1;
    #pragma unroll
    for (int j = 0; j < 4; ++j) {
        #pragma unroll
        for (int q = 0; q < 4; ++q) {
            float4 wa = W1v[(4 * lane + j) * 4 + q];
            wA[j][4 * q + 0] = wa.x; wA[j][4 * q + 1] = wa.y;
            wA[j][4 * q + 2] = wa.z; wA[j][4 * q + 3] = wa.w;
            float4 wb = W1v[(256 + 4 * lane + j) * 4 + q];
            wB[j][4 * q + 0] = wb.x; wB[j][4 * q + 1] = wb.y;
            wB[j][4 * q + 2] = wb.z; wB[j][4 * q + 3] = wb.w;
        }
    }

    const float4* xv = (const float4*)x;
    const int stride = gridDim.x * 4;

    auto process = [&](float4 p0, float4 p1, int r) {
        float part[16];
        #pragma unroll
        for (int c = 0; c < 16; ++c) part[c] = 0.f;
        float av[8] = {p0.x, p0.y, p0.z, p0.w, p1.x, p1.y, p1.z, p1.w};
        #pragma unroll
        for (int j = 0; j < 4; ++j) {
            #pragma unroll
            for (int c = 0; c < 16; ++c) {
                part[c] = fmaf(av[j], wA[j][c], part[c]);
                part[c] = fmaf(av[4 + j], wB[j][c], part[c]);
            }
        }
        const bool h5 = (lane & 32) != 0;
        float v8[8];
        #pragma unroll
        for (int j = 0; j < 8; ++j)
            v8[j] = (h5 ? part[j + 8] : part[j]) +
                    __shfl_xor(h5 ? part[j] : part[j + 8], 32, 64);
        const bool h4 = (lane & 16) != 0;
        float v4[4];
        #pragma unroll
        for (int j = 0; j < 4; ++j)
            v4[j] = (h4 ? v8[j + 4] : v8[j]) +
                    __shfl_xor(h4 ? v8[j] : v8[j + 4], 16, 64);
        const bool h3 = (lane & 8) != 0;
        float v2[2];
        #pragma unroll
        for (int j = 0; j < 2; ++j)
            v2[j] = (h3 ? v4[j + 2] : v4[j]) +
                    __shfl_xor(h3 ? v4[j] : v4[j + 2], 8, 64);
        const bool h2 = (lane & 4) != 0;
        float v1 = (h2 ? v2[1] : v2[0]) +
                   __shfl_xor(h2 ? v2[0] : v2[1], 4, 64);
        v1 += __shfl_xor(v1, 2, 64);
        v1 += __shfl_xor(v1, 1, 64);
        // every lane holds col (lane>>2); pair up cols (2p,2p+1) on lanes 8p
        float vnext = __shfl_down(v1, 4, 64);
        if ((lane & 7) == 0) {
            float di = dinv[r];
            h1s[(size_t)r * 8 + (lane >> 3)] = packbf(di * v1, di * vnext);
        }
    };

    int r0 = blockIdx.x * 4 + wav;
    int r1 = r0 + stride;
    float4 a0, a1, b0, b1;
    if (r0 < n) {
        a0 = xv[(size_t)r0 * 128 + lane];
        a1 = xv[(size_t)r0 * 128 + 64 + lane];
    }
    if (r1 < n) {
        b0 = xv[(size_t)r1 * 128 + lane];
        b1 = xv[(size_t)r1 * 128 + 64 + lane];
    }

    while (r0 < n) {
        float4 ca0 = a0, ca1 = a1;
        int pr = r0 + 2 * stride;
        if (pr < n) {
            a0 = xv[(size_t)pr * 128 + lane];
            a1 = xv[(size_t)pr * 128 + 64 + lane];
        }
        process(ca0, ca1, r0);
        if (r1 < n) {
            float4 cb0 = b0, cb1 = b1;
            int pr2 = r1 + 2 * stride;
            if (pr2 < n) {
                b0 = xv[(size_t)pr2 * 128 + lane];
                b1 = xv[(size_t)pr2 * 128 + 64 + lane];
            }
            process(cb0, cb1, r1);
        }
        r0 += 2 * stride;
        r1 += 2 * stride;
    }
}

// ---------------- gather1: 8 lanes/node = 4 segs x 2 halves, uint4, 4-deep ILP ----------

__global__ __launch_bounds__(256) void k_gather1(
    const int2* __restrict__ oe, const int* __restrict__ csr,
    const uint4* __restrict__ h1s, const float* __restrict__ dinv,
    const float* __restrict__ b1, uint4* __restrict__ hs2, int n) {
    int t = blockIdx.x * 256 + threadIdx.x;
    int node = t >> 3;
    if (node >= n) return;
    const int sub = t & 7, seg = sub >> 1, p = sub & 1;
    int2 r = oe[node];
    const int d = r.y - r.x;
    int j = r.x + ((d * seg) >> 2);
    const int e = r.x + ((d * (seg + 1)) >> 2);
    const char* tab = (const char*)h1s;
    const unsigned pof = (unsigned)(p << 4);

    float A[8], B[8];
    #pragma unroll
    for (int k = 0; k < 8; ++k) { A[k] = 0.f; B[k] = 0.f; }
    if (seg == 0) {  // self loop
        uint4 su = *(const uint4*)(tab + (((unsigned)node << 5) | pof));
        ACC8(A, su);
    }
    for (; j + 3 < e; j += 4) {
        int i0 = csr[j], i1 = csr[j + 1], i2 = csr[j + 2], i3 = csr[j + 3];
        uint4 u0 = *(const uint4*)(tab + (((unsigned)i0 << 5) | pof));
        uint4 u1 = *(const uint4*)(tab + (((unsigned)i1 << 5) | pof));
        uint4 u2 = *(const uint4*)(tab + (((unsigned)i2 << 5) | pof));
        uint4 u3 = *(const uint4*)(tab + (((unsigned)i3 << 5) | pof));
        ACC8(A, u0); ACC8(B, u1); ACC8(A, u2); ACC8(B, u3);
    }
    for (; j < e; ++j) {
        uint4 u = *(const uint4*)(tab + (((unsigned)csr[j] << 5) | pof));
        ACC8(A, u);
    }
    float v[8];
    #pragma unroll
    for (int k = 0; k < 8; ++k) v[k] = A[k] + B[k];
    #pragma unroll
    for (int k = 0; k < 8; ++k) {
        v[k] += __shfl_xor(v[k], 2, 64);
        v[k] += __shfl_xor(v[k], 4, 64);
    }
    if (seg == 0) {
        float di = dinv[node];
        const float4* b1v = (const float4*)b1;
        float4 q0 = b1v[2 * p], q1 = b1v[2 * p + 1];
        float bias[8] = {q0.x, q0.y, q0.z, q0.w, q1.x, q1.y, q1.z, q1.w};
        float o[8];
        #pragma unroll
        for (int k = 0; k < 8; ++k)
            o[k] = di * fmaxf(fmaf(di, v[k], bias[k]), 0.f);
        uint4 w;
        w.x = packbf(o[0], o[1]); w.y = packbf(o[2], o[3]);
        w.z = packbf(o[4], o[5]); w.w = packbf(o[6], o[7]);
        *(uint4*)((char*)hs2 + (((unsigned)node << 5) | pof)) = w;
    }
}

// ---------------- fused gather2 + W2 + b2 + log_softmax ----------------
// Phase 1: same 8-lanes/node seg-split gather. Phase 2: 8 nodes/wave MLP+softmax.

__global__ __launch_bounds__(256) void k_g2f(
    const int2* __restrict__ oe, const int* __restrict__ csr,
    const uint4* __restrict__ hs2, const float* __restrict__ dinv,
    const float* __restrict__ W2, const float* __restrict__ b2,
    float* __restrict__ out, int n) {
    __shared__ float w2s[NF1 * NF2];
    __shared__ float b2s[NF2];
    __shared__ float agg[32][17];
    for (int i = threadIdx.x; i < NF1 * NF2; i += 256) w2s[i] = W2[i];
    if (threadIdx.x < NF2) b2s[threadIdx.x] = b2[threadIdx.x];

    int t = blockIdx.x * 256 + threadIdx.x;
    int node = t >> 3;
    const int sub = t & 7, seg = sub >> 1, p = sub & 1;
    const int g = threadIdx.x >> 3;

    if (node < n) {
        int2 r = oe[node];
        const int d = r.y - r.x;
        int j = r.x + ((d * seg) >> 2);
        const int e = r.x + ((d * (seg + 1)) >> 2);
        const char* tab = (const char*)hs2;
        const unsigned pof = (unsigned)(p << 4);

        float A[8], B[8];
        #pragma unroll
        for (int k = 0; k < 8; ++k) { A[k] = 0.f; B[k] = 0.f; }
        if (seg == 0) {  // self loop
            uint4 su = *(const uint4*)(tab + (((unsigned)node << 5) | pof));
            ACC8(A, su);
        }
        for (; j + 3 < e; j += 4) {
            int i0 = csr[j], i1 = csr[j + 1], i2 = csr[j + 2], i3 = csr[j + 3];
            uint4 u0 = *(const uint4*)(tab + (((unsigned)i0 << 5) | pof));
            uint4 u1 = *(const uint4*)(tab + (((unsigned)i1 << 5) | pof));
            uint4 u2 = *(const uint4*)(tab + (((unsigned)i2 << 5) | pof));
            uint4 u3 = *(const uint4*)(tab + (((unsigned)i3 << 5) | pof));
            ACC8(A, u0); ACC8(B, u1); ACC8(A, u2); ACC8(B, u3);
        }
        for (; j < e; ++j) {
            uint4 u = *(const uint4*)(tab + (((unsigned)csr[j] << 5) | pof));
            ACC8(A, u);
        }
        float v[8];
        #pragma unroll
        for (int k = 0; k < 8; ++k) v[k] = A[k] + B[k];
        #pragma unroll
        for (int k = 0; k < 8; ++k) {
            v[k] += __shfl_xor(v[k], 2, 64);
            v[k] += __shfl_xor(v[k], 4, 64);
        }
        if (seg == 0) {
            float di = dinv[node];
            #pragma unroll
            for (int k = 0; k < 8; ++k) agg[g][8 * p + k] = v[k] * di;
        }
    }
    __syncthreads();

    int wav = threadIdx.x >> 6, lane = threadIdx.x & 63;
    int nbase = blockIdx.x * 32 + wav * 8;
    #pragma unroll
    for (int q = 0; q < 8; ++q) {
        int nd = nbase + q;
        if (nd >= n) break;  // nd uniform across wave
        float av[16];
        #pragma unroll
        for (int k = 0; k < 16; ++k) av[k] = agg[wav * 8 + q][k];
        float d = -1e30f;
        if (lane < NF2) {
            d = b2s[lane];
            #pragma unroll
            for (int k = 0; k < 16; ++k) d = fmaf(av[k], w2s[k * NF2 + lane], d);
        }
        float m = d;
        #pragma unroll
        for (int off = 32; off; off >>= 1) m = fmaxf(m, __shfl_xor(m, off, 64));
        float e2 = (lane < NF2) ? __expf(d - m) : 0.f;
        float ssum = e2;
        #pragma unroll
        for (int off = 32; off; off >>= 1) ssum += __shfl_xor(ssum, off, 64);
        float ls = __logf(ssum);
        if (lane < NF2) out[(size_t)nd * NF2 + lane] = d - m - ls;
    }
}

// ---------------- launch ----------------

extern "C" void kernel_launch(void* const* d_in, const int* in_sizes, int n_in,
                              void* d_out, int out_size, void* d_ws, size_t ws_size,
                              hipStream_t stream) {
    const float* x  = (const float*)d_in[0];
    const int*   ei = (const int*)d_in[1];
    const float* W1 = (const float*)d_in[2];
    const float* b1 = (const float*)d_in[3];
    const float* W2 = (const float*)d_in[4];
    const float* b2 = (const float*)d_in[5];
    float* out = (float*)d_out;

    const int N = in_sizes[0] / NF0;  // 100000
    const int E = in_sizes[1] / 2;    // 3200000
    const int NB = (N + BNODES - 1) / BNODES;  // 782
    const int* src = ei;
    const int* dst = ei + E;

    char* ws = (char*)d_ws;
    size_t off = 0;
    auto alloc = [&](size_t bytes) -> void* {
        void* p = ws + off;
        off = (off + bytes + 255) & ~(size_t)255;
        return p;
    };
    int*   cursor = (int*)alloc((size_t)NB * 4);
    unsigned int* binned = (unsigned int*)alloc((size_t)NB * MAXPB * 4);
    int*   csr    = (int*)alloc((size_t)NB * MAXPB * 4);
    int2*  oe     = (int2*)alloc((size_t)N * 8);
    float* dinv   = (float*)alloc((size_t)N * 4);
    // binned dead after k_build: reuse for bf16 h1s/hs2 (3.2MB each)
    unsigned int* h1s = binned;
    unsigned int* hs2 = binned + (size_t)N * 8;

    const int eb = (E + CHUNK - 1) / CHUNK;  // 391
    const size_t histBytes = (size_t)NB * 4;
    const int gblocks = (N * 8 + 255) / 256;  // 8 lanes/node

    k_zero   <<<(NB + 255) / 256, 256, 0, stream>>>(cursor, NB);
    k_binsort<<<eb, 256, 3 * histBytes, stream>>>(src, dst, cursor, binned, E, NB);
    k_build  <<<NB, 256, 0, stream>>>(binned, cursor, csr, oe, dinv, N);
    k_gemm1  <<<1024, 256, 0, stream>>>(x, W1, dinv, h1s, N);
    k_gather1<<<gblocks, 256, 0, stream>>>(oe, csr, (const uint4*)h1s, dinv, b1,
                                           (uint4*)hs2, N);
    k_g2f    <<<gblocks, 256, 0, stream>>>(oe, csr, (const uint4*)hs2, dinv, W2, b2,
                                           out, N);
}